// Round 18
// baseline (390.171 us; speedup 1.0000x reference)
//
#include <hip/hip_runtime.h>
#include <hip/hip_bf16.h>
#include <math.h>

#define L_SZ 1024
#define STRIDE_ 32
#define WIN 8
#define PNUM 31
#define NPATCH 31744   // 1024 batches x 31 patches
#define SGRID 512      // 256 CU x 2 blocks/CU co-resident ((256,2)-pinned residency)

// LDS row strides (in shorts). dword strides = 36/68 = 4 mod 32 -> 2-way banks (free).
#define X1TS 72
#define CAS  136

typedef __attribute__((ext_vector_type(8))) short short8;
typedef __attribute__((ext_vector_type(4))) short short4v;
typedef __attribute__((ext_vector_type(4))) float f32x4;

#define MFMA16(a, b, c) __builtin_amdgcn_mfma_f32_16x16x32_bf16(a, b, c, 0, 0, 0)

// LDS-only barrier: waits lgkmcnt only; vmem stays in flight across the
// barrier (compiler inserts vmcnt waits before first USE of loaded values).
// sched_barrier(0) fences both sides (rule #18).
__device__ __forceinline__ void bar_lds() {
    __builtin_amdgcn_sched_barrier(0);
    asm volatile("s_waitcnt lgkmcnt(0)" ::: "memory");
    __builtin_amdgcn_s_barrier();
    __builtin_amdgcn_sched_barrier(0);
}

__device__ __forceinline__ float sigf(float x) { return 1.0f / (1.0f + __expf(-x)); }
__device__ __forceinline__ float tanhfast(float x) {
    float ax = fabsf(x);
    float t = __expf(-2.0f * ax);
    return copysignf((1.0f - t) / (1.0f + t), x);
}
__device__ __forceinline__ short f2bf(float f) {
    __hip_bfloat16 h = __float2bfloat16(f);   // RNE
    return *reinterpret_cast<short*>(&h);
}
__device__ __forceinline__ float bf2f(short s) {
    __hip_bfloat16 h = *reinterpret_cast<__hip_bfloat16*>(&s);
    return __bfloat162float(h);
}

// row degree-inverse of the banded sigmoid adjacency, ascending-j order —
// bit-identical to the original adj_kernel (out-of-band terms were exact 0.0f).
__device__ __forceinline__ float deg_inv_row(const float* __restrict__ ew, int row) {
    float s = 0.f;
    #pragma unroll
    for (int d = 0; d < 17; ++d) {
        int j = row + d - WIN;
        if (j >= 0 && j < 64 && d != WIN) s += sigf(ew[row * 64 + j]);
    }
    return (s > 0.f) ? 1.0f / s : 0.f;
}

// ---------------------------------------------------------------------------
// prep (R33): adjn production moved here (block 234) — R32 computed areg
// inline in sage, which put 34 sigmoids + ew loads on every sage block's
// critical path (+6 us). Now prep writes adjn (same expression, ascending-j
// order -> bit-identical to the old adj_kernel) and sage loads it (R31 form,
// measured 181 us).
//   blocks   0..31  : wihf0 | 32..95 : wihf1 | 96..105 : sage frags
//   blocks 106..169 : Whh0  | 170..233 : Whh1 | 234 : adjn
// ---------------------------------------------------------------------------
__global__ void prep_kernel(const float* __restrict__ Wih0, const float* __restrict__ Whh0,
                            const float* __restrict__ Wih1, const float* __restrict__ Whh1,
                            const float* __restrict__ ew, float* __restrict__ adjn,
                            const float* __restrict__ Ws2, const float* __restrict__ Wn2,
                            short* __restrict__ wihf0G, short* __restrict__ wihf1G,
                            short* __restrict__ adjfG, short* __restrict__ wcatfG,
                            short* __restrict__ whhf0G, short* __restrict__ whhf1G) {
    int bid = blockIdx.x, tid = threadIdx.x;
    if (bid < 32) {                      // wihf0: f = nt*4 + ks*2 + hl (K32=2)
        int t = bid * 256 + tid;         // 0..8191
        int f = t >> 6, l = t & 63;
        int hl = f & 1, ks = (f >> 1) & 1, nt = f >> 2;
        int q = l >> 4, l15 = l & 15;
        short8 v;
        #pragma unroll
        for (int e = 0; e < 8; ++e) {
            float src = Wih0[(size_t)(nt * 16 + l15) * 64 + ks * 32 + 8 * q + e];
            short hi = f2bf(src);
            v[e] = hl ? f2bf(src - bf2f(hi)) : hi;
        }
        *(short8*)(wihf0G + (size_t)f * 512 + l * 8) = v;
        return;
    }
    if (bid < 96) {                      // wihf1: f = nt*8 + ks*2 + hl (K32=4)
        int t = (bid - 32) * 256 + tid;  // 0..16383
        int f = t >> 6, l = t & 63;
        int hl = f & 1, ks = (f >> 1) & 3, nt = f >> 3;
        int q = l >> 4, l15 = l & 15;
        short8 v;
        #pragma unroll
        for (int e = 0; e < 8; ++e) {
            float src = Wih1[(size_t)(nt * 16 + l15) * 128 + ks * 32 + 8 * q + e];
            short hi = f2bf(src);
            v[e] = hl ? f2bf(src - bf2f(hi)) : hi;
        }
        *(short8*)(wihf1G + (size_t)f * 512 + l * 8) = v;
        return;
    }
    if (bid < 106) {
        int t = (bid - 96) * 256 + tid;
        if (t >= 2432) return;
        int f = t >> 6, l = t & 63;
        int q = l >> 4, l15 = l & 15;
        short8 v;
        if (f < 6) {
            const int ntT[6] = {0, 1, 1, 2, 2, 3};
            const int ksT[6] = {0, 0, 1, 0, 1, 1};
            int row = l15 + 16 * ntT[f], col = 8 * q + 32 * ksT[f];
            float dinv = deg_inv_row(ew, row);
            #pragma unroll
            for (int e = 0; e < 8; ++e) {
                int c = col + e;
                int dd = row - c; dd = dd < 0 ? -dd : dd;
                float av = (dd <= WIN && dd != 0) ? sigf(ew[row * 64 + c]) * dinv : 0.f;
                v[e] = f2bf(av);
            }
            *(short8*)(adjfG + ((size_t)f * 64 + l) * 8) = v;
        } else {
            int fi = f - 6;
            int isLo = fi >= 16;
            int ff = isLo ? fi - 16 : fi;
            int nt = ff >> 2, ks = ff & 3;
            int oo = l15 + 16 * nt;
            #pragma unroll
            for (int e = 0; e < 8; ++e) {
                int k = 32 * ks + 8 * q + e;
                float src = (k < 64) ? Ws2[oo * 64 + k] : Wn2[oo * 64 + (k - 64)];
                short hi = f2bf(src);
                v[e] = isLo ? f2bf(src - bf2f(hi)) : hi;
            }
            *(short8*)(wcatfG + ((size_t)fi * 64 + l) * 8) = v;
        }
        return;
    }
    if (bid < 234) {
        int layer = (bid < 170) ? 0 : 1;
        int base = layer ? 170 : 106;
        const float* Whh = layer ? Whh1 : Whh0;
        short* dst = layer ? whhf1G : whhf0G;
        int t = (bid - base) * 256 + tid;    // 0..16383
        int frag = t >> 6, l = t & 63;
        int hl = frag & 1, ks = (frag >> 1) & 3, NT = frag >> 3;
        int g = NT * 16 + (l & 15);
        int kbase = ks * 32 + (l >> 4) * 8;
        short8 v;
        #pragma unroll
        for (int e = 0; e < 8; ++e) {
            float src = Whh[(size_t)g * 128 + kbase + e];
            short hi = f2bf(src);
            v[e] = hl ? f2bf(src - bf2f(hi)) : hi;
        }
        *(short8*)(dst + (size_t)t * 8) = v;
        return;
    }
    {
        // block 234: adjn[i][j] — 4096 entries, 16 per thread (one row per
        // 4-thread group). Same expression & order as the old adj_kernel.
        int i = tid >> 2;                 // row 0..63
        int j0 = (tid & 3) * 16;          // 16 cols per thread
        float dinv = deg_inv_row(ew, i);
        #pragma unroll
        for (int e = 0; e < 16; ++e) {
            int j = j0 + e;
            int d = i - j; d = d < 0 ? -d : d;
            float a = (d <= WIN && d != 0) ? sigf(ew[i * 64 + j]) : 0.f;
            adjn[i * 64 + j] = a * dinv;
        }
    }
}

// ---------------------------------------------------------------------------
// Persistent fused SAGE, bf16 MFMA. R33 = exact R31 body (best measured for
// sage: 181 us, VGPR 116, FETCH 8.2 MB): areg loaded from prep-written adjn
// (L2-resident) instead of R32's inline sigmoid recompute (+6 us on the
// block critical path). adj_kernel launch stays eliminated.
// ---------------------------------------------------------------------------
__launch_bounds__(256, 2)
__global__ void sage_mfma(const float* __restrict__ I, const float* __restrict__ Q,
                          const float* __restrict__ adjn,
                          const float* __restrict__ Wn1, const float* __restrict__ bn1,
                          const float* __restrict__ Ws1, const float* __restrict__ bs1,
                          const float* __restrict__ bn2, const float* __restrict__ bs2,
                          const short* __restrict__ adjfG, const short* __restrict__ wcatfG,
                          float* __restrict__ feats) {
    __shared__ __align__(16) short s_x1T[2][64 * X1TS];  // x1^T [o][i] bf16, per patch
    __shared__ __align__(16) short s_cat[2][64 * CAS];   // [i][x1|n1] bf16, per patch

    const int tid = threadIdx.x;
    const int w = tid >> 6, l = tid & 63, q = l >> 4, l15 = l & 15;

    const bool hasKs0 = (w <= 2);
    const bool hasKs1 = (w >= 1);
    const int idx0 = (w == 0) ? 0 : (w == 1 ? 1 : 3);
    const int idx1 = (w == 1) ? 2 : (w == 2 ? 4 : 5);
    short8 adjB0 = {}, adjB1 = {};
    if (hasKs0) adjB0 = *(const short8*)(adjfG + ((size_t)idx0 * 64 + l) * 8);
    if (hasKs1) adjB1 = *(const short8*)(adjfG + ((size_t)idx1 * 64 + l) * 8);

    short8 whf[4], wlf[4];
    #pragma unroll
    for (int ks = 0; ks < 4; ++ks) {
        whf[ks] = *(const short8*)(wcatfG + ((size_t)(w * 4 + ks) * 64 + l) * 8);
        wlf[ks] = *(const short8*)(wcatfG + ((size_t)(w * 4 + ks + 16) * 64 + l) * 8);
    }
    const int oo = l15 + 16 * w;
    const float bo = bs2[oo] + bn2[oo];

    // adjn band in registers: lane l = row i; zeros outside [0,64)
    float areg[17];
    #pragma unroll
    for (int d = 0; d < 17; ++d) {
        int j = l + d - WIN;
        areg[d] = (j >= 0 && j < 64) ? adjn[l * 64 + j] : 0.f;
    }

    float x0a[2], x0b[2];
    #pragma unroll
    for (int P = 0; P < 2; ++P) {
        int m = blockIdx.x + P * 512;
        int b = m / PNUM, p = m % PNUM;
        x0a[P] = I[(size_t)b * L_SZ + p * STRIDE_ + l];
        x0b[P] = Q[(size_t)b * L_SZ + p * STRIDE_ + l];
    }

    for (int it = 0; it < 31; ++it) {
        const int m0 = it * 1024 + blockIdx.x;

        #pragma unroll
        for (int P = 0; P < 2; ++P) {
            float n0a = 0.f, n0b = 0.f;
            #pragma unroll
            for (int d = 0; d < 17; ++d) {
                int j = l + d - WIN;
                float xa = __shfl(x0a[P], j, 64);
                float xb = __shfl(x0b[P], j, 64);
                n0a += areg[d] * xa;
                n0b += areg[d] * xb;
            }
            union { short s[16]; short8 v[2]; } pk;
            #pragma unroll
            for (int t = 0; t < 16; ++t) {
                int o = w * 16 + t;
                float2 wsv = ((const float2*)Ws1)[o];
                float2 wnv = ((const float2*)Wn1)[o];
                float v = bs1[o] + bn1[o] + wsv.x * x0a[P] + wsv.y * x0b[P]
                                          + wnv.x * n0a + wnv.y * n0b;
                v = fmaxf(v, 0.f);
                short bv = f2bf(v);
                s_x1T[P][o * X1TS + l] = bv;
                pk.s[t] = bv;
            }
            *(short8*)&s_cat[P][l * CAS + w * 16]     = pk.v[0];
            *(short8*)&s_cat[P][l * CAS + w * 16 + 8] = pk.v[1];
        }

        if (it + 1 < 31) {
            #pragma unroll
            for (int P = 0; P < 2; ++P) {
                int m = (it + 1) * 1024 + blockIdx.x + P * 512;
                int b = m / PNUM, p = m % PNUM;
                x0a[P] = I[(size_t)b * L_SZ + p * STRIDE_ + l];
                x0b[P] = Q[(size_t)b * L_SZ + p * STRIDE_ + l];
            }
        }
        bar_lds();

        #pragma unroll
        for (int P = 0; P < 2; ++P) {
            #pragma unroll
            for (int ot = 0; ot < 4; ++ot) {
                f32x4 c = {0.f, 0.f, 0.f, 0.f};
                if (hasKs0) {
                    short8 a = *(const short8*)&s_x1T[P][(16 * ot + l15) * X1TS + 8 * q];
                    c = MFMA16(a, adjB0, c);
                }
                if (hasKs1) {
                    short8 a = *(const short8*)&s_x1T[P][(16 * ot + l15) * X1TS + 8 * q + 32];
                    c = MFMA16(a, adjB1, c);
                }
                short4v nv;
                nv[0] = f2bf(c[0]); nv[1] = f2bf(c[1]);
                nv[2] = f2bf(c[2]); nv[3] = f2bf(c[3]);
                *(short4v*)&s_cat[P][(16 * w + l15) * CAS + 64 + 16 * ot + 4 * q] = nv;
            }
        }
        bar_lds();

        #pragma unroll
        for (int P = 0; P < 2; ++P) {
            f32x4 z = {0.f, 0.f, 0.f, 0.f};
            f32x4 acc2[4] = {z, z, z, z};
            #pragma unroll
            for (int it2 = 0; it2 < 4; ++it2) {
                short8 a2[4];
                #pragma unroll
                for (int ks = 0; ks < 4; ++ks)
                    a2[ks] = *(const short8*)&s_cat[P][(16 * it2 + l15) * CAS + 32 * ks + 8 * q];
                #pragma unroll
                for (int ks = 0; ks < 4; ++ks) {
                    acc2[it2] = MFMA16(a2[ks], whf[ks], acc2[it2]);
                    acc2[it2] = MFMA16(a2[ks], wlf[ks], acc2[it2]);
                }
            }
            float total = 0.f;
            #pragma unroll
            for (int it2 = 0; it2 < 4; ++it2) {
                float s = fmaxf(acc2[it2][0] + bo, 0.f) + fmaxf(acc2[it2][1] + bo, 0.f)
                        + fmaxf(acc2[it2][2] + bo, 0.f) + fmaxf(acc2[it2][3] + bo, 0.f);
                s += __shfl_xor(s, 16);
                s += __shfl_xor(s, 32);
                total += s;
            }
            if (l < 16)
                feats[(size_t)(m0 + P * 512) * 64 + 16 * w + l15] = total;
        }
        bar_lds();
    }
}

// ---------------------------------------------------------------------------
// GEMM v2 (R27): MFMA with double-bf16 (hi/lo) on BOTH operands, 3-term
// product. C[M x 512] = A[M x K] @ Wih^T + b1 + b2. (control)
// ---------------------------------------------------------------------------
template <int K>
__launch_bounds__(256, 2)
__global__ void gemm_mfma(const float* __restrict__ A, const short* __restrict__ wihfG,
                          const float* __restrict__ bias1, const float* __restrict__ bias2,
                          float* __restrict__ C) {
    constexpr int K32 = K / 32;
    constexpr int K4 = K / 4;
    constexpr int AS = (K == 64) ? 72 : 136;   // row stride in shorts (4-mod-32 dwords)
    __shared__ __align__(16) short s_ah[64 * AS];
    __shared__ __align__(16) short s_al[64 * AS];
    const int tid = threadIdx.x;
    const int w = tid >> 6, l = tid & 63, q = l >> 4, l15 = l & 15;
    const int m0 = blockIdx.x * 64;
    const int j0 = blockIdx.y * 128;

    // stage A hi/lo into LDS (64 rows x K floats -> 2x bf16)
    {
        const float4* Ag = (const float4*)(A + (size_t)m0 * K);
        for (int e = tid; e < 16 * K; e += 256) {
            int row = e / K4, c4 = e % K4;
            float4 v = Ag[row * K4 + c4];
            short4v h, lo;
            h[0] = f2bf(v.x); lo[0] = f2bf(v.x - bf2f(h[0]));
            h[1] = f2bf(v.y); lo[1] = f2bf(v.y - bf2f(h[1]));
            h[2] = f2bf(v.z); lo[2] = f2bf(v.z - bf2f(h[2]));
            h[3] = f2bf(v.w); lo[3] = f2bf(v.w - bf2f(h[3]));
            *(short4v*)&s_ah[row * AS + c4 * 4] = h;
            *(short4v*)&s_al[row * AS + c4 * 4] = lo;
        }
    }

    // B frags: wave w owns global ntiles (j0/16 + 2w) and (j0/16 + 2w + 1)
    short8 bh[2][K32], bl[2][K32];
    #pragma unroll
    for (int c = 0; c < 2; ++c) {
        int nt = (j0 >> 4) + 2 * w + c;
        #pragma unroll
        for (int ks = 0; ks < K32; ++ks) {
            bh[c][ks] = *(const short8*)(wihfG + (((size_t)(nt * K32 + ks) * 2 + 0) * 64 + l) * 8);
            bl[c][ks] = *(const short8*)(wihfG + (((size_t)(nt * K32 + ks) * 2 + 1) * 64 + l) * 8);
        }
    }
    __syncthreads();

    f32x4 z = {0.f, 0.f, 0.f, 0.f};
    #pragma unroll
    for (int mt = 0; mt < 4; ++mt) {
        f32x4 acc[2] = {z, z};
        #pragma unroll
        for (int ks = 0; ks < K32; ++ks) {
            short8 ah = *(const short8*)&s_ah[(16 * mt + l15) * AS + 32 * ks + 8 * q];
            short8 al = *(const short8*)&s_al[(16 * mt + l15) * AS + 32 * ks + 8 * q];
            #pragma unroll
            for (int c = 0; c < 2; ++c) {
                acc[c] = MFMA16(ah, bh[c][ks], acc[c]);
                acc[c] = MFMA16(al, bh[c][ks], acc[c]);
                acc[c] = MFMA16(ah, bl[c][ks], acc[c]);
            }
        }
        #pragma unroll
        for (int c = 0; c < 2; ++c) {
            int col = j0 + (2 * w + c) * 16 + l15;
            float bo = bias1[col] + bias2[col];
            #pragma unroll
            for (int reg = 0; reg < 4; ++reg) {
                int row = m0 + 16 * mt + 4 * q + reg;
                C[(size_t)row * 512 + col] = acc[c][reg] + bo;
            }
        }
    }
}

// ---------------------------------------------------------------------------
// LSTM recurrence v9 (R29): remapped tiles + shuffle-spread in-register gates.
// (control — unchanged from R29/R31)
// ---------------------------------------------------------------------------
#define HS 136    // s_h row stride in shorts (68 dwords = 4 mod 32)

template <bool FINAL>
__launch_bounds__(512)
__global__ void lstm_mfma(const float* __restrict__ xg, const short* __restrict__ whhfG,
                          float* __restrict__ out0,
                          const float* __restrict__ Wc1, const float* __restrict__ bc1,
                          const float* __restrict__ Wc2, const float* __restrict__ bc2,
                          float* __restrict__ out) {
    __shared__ __align__(16) short s_h[16 * HS];    // h bf16 [m][k]; rows 4..15 stay 0
    __shared__ __align__(16) float s_hid[4 * 68];
    const int tid = threadIdx.x;
    const int w = tid >> 6, l = tid & 63, quad = l >> 4, l15 = l & 15;
    const int b0 = blockIdx.x * 4;                  // 4 batch rows per block
    const int j = 16 * w + l15;                     // this lane's hidden unit 0..127
    const int row = quad;                           // this lane's batch row 0..3

    // weight frags for output tiles NT = w + 8*nt  (nt = 0:i, 1:f, 2:g, 3:o)
    short8 whf[16], wlf[16];
    #pragma unroll
    for (int nt = 0; nt < 4; ++nt)
        #pragma unroll
        for (int ks = 0; ks < 4; ++ks) {
            size_t NT = (size_t)(w + 8 * nt);
            whf[nt * 4 + ks] = *(const short8*)(whhfG + (((NT * 4 + ks) * 2 + 0) * 64 + l) * 8);
            wlf[nt * 4 + ks] = *(const short8*)(whhfG + (((NT * 4 + ks) * 2 + 1) * 64 + l) * 8);
        }

    float c0 = 0.f;
    for (int e = tid; e < 16 * HS; e += 512) s_h[e] = 0;
    __syncthreads();

    // prefetch t=0 xgv for (row, unit j)
    float xgv[4];
    {
        size_t base = ((size_t)(b0 + row) * PNUM + 0) * 512 + j;
        xgv[0] = xg[base];
        xgv[1] = xg[base + 128];
        xgv[2] = xg[base + 256];
        xgv[3] = xg[base + 384];
    }

    for (int t = 0; t < 31; ++t) {
        short8 af[4];
        #pragma unroll
        for (int ks = 0; ks < 4; ++ks)
            af[ks] = *(const short8*)&s_h[l15 * HS + ks * 32 + quad * 8];
        bar_lds();   // #1: all waves' af reads retired before any s_h overwrite

        f32x4 z = {0.f, 0.f, 0.f, 0.f};
        f32x4 acc[4] = {z, z, z, z};
        #pragma unroll
        for (int nt = 0; nt < 4; ++nt)
            #pragma unroll
            for (int ks = 0; ks < 4; ++ks) {
                acc[nt] = MFMA16(af[ks], whf[nt * 4 + ks], acc[nt]);
                acc[nt] = MFMA16(af[ks], wlf[nt * 4 + ks], acc[nt]);
            }

        // issue next-step xgv loads: in flight across gates + barrier
        float nx0 = 0.f, nx1 = 0.f, nx2 = 0.f, nx3 = 0.f;
        if (t + 1 < 31) {
            size_t base = ((size_t)(b0 + row) * PNUM + (t + 1)) * 512 + j;
            nx0 = xg[base];
            nx1 = xg[base + 128];
            nx2 = xg[base + 256];
            nx3 = xg[base + 384];
        }

        // shuffle-broadcast: gate nt for (row, j) = acc[nt][row], held by lane l15
        float g4[4];
        #pragma unroll
        for (int nt = 0; nt < 4; ++nt) {
            float s0 = __shfl(acc[nt][0], l15, 64);
            float s1 = __shfl(acc[nt][1], l15, 64);
            float s2 = __shfl(acc[nt][2], l15, 64);
            float s3 = __shfl(acc[nt][3], l15, 64);
            g4[nt] = (quad == 0) ? s0 : (quad == 1) ? s1 : (quad == 2) ? s2 : s3;
        }

        // gates: every lane handles one (row, unit)
        {
            float gi = xgv[0] + g4[0];
            float gf = xgv[1] + g4[1];
            float gg = xgv[2] + g4[2];
            float go = xgv[3] + g4[3];
            float cn = sigf(gf) * c0 + sigf(gi) * tanhfast(gg);
            float h = sigf(go) * tanhfast(cn);
            c0 = cn;
            s_h[row * HS + j] = f2bf(h);
            if (!FINAL)
                out0[((size_t)(b0 + row) * PNUM + t) * 128 + j] = h;
        }
        xgv[0] = nx0; xgv[1] = nx1; xgv[2] = nx2; xgv[3] = nx3;
        bar_lds();   // #2: s_h writes visible before next step's af reads
    }

    if (FINAL) {
        if (tid < 256) {
            int rr = tid >> 6, uu = tid & 63;
            float acc = bc1[uu];
            const float* wv = Wc1 + (size_t)uu * 128;
            #pragma unroll 8
            for (int k = 0; k < 128; ++k) acc += wv[k] * bf2f(s_h[rr * HS + k]);
            s_hid[rr * 68 + uu] = fmaxf(acc, 0.f);
        }
        __syncthreads();
        if (tid < 44) {
            int rr = tid / 11, cc = tid % 11;
            float acc = bc2[cc];
            #pragma unroll
            for (int uu = 0; uu < 64; ++uu) acc += Wc2[cc * 64 + uu] * s_hid[rr * 68 + uu];
            out[(size_t)(b0 + rr) * 11 + cc] = acc;
        }
    }
}

// ---------------------------------------------------------------------------
extern "C" void kernel_launch(void* const* d_in, const int* in_sizes, int n_in,
                              void* d_out, int out_size, void* d_ws, size_t ws_size,
                              hipStream_t stream) {
    (void)in_sizes; (void)n_in; (void)out_size; (void)ws_size;
    const float* I    = (const float*)d_in[0];
    const float* Q    = (const float*)d_in[1];
    const float* ew   = (const float*)d_in[2];
    const float* Wn1  = (const float*)d_in[3];
    const float* bn1  = (const float*)d_in[4];
    const float* Ws1  = (const float*)d_in[5];
    const float* bs1  = (const float*)d_in[6];
    const float* Wn2  = (const float*)d_in[7];
    const float* bn2  = (const float*)d_in[8];
    const float* Ws2  = (const float*)d_in[9];
    const float* bs2  = (const float*)d_in[10];
    const float* Wih0 = (const float*)d_in[11];
    const float* Whh0 = (const float*)d_in[12];
    const float* bih0 = (const float*)d_in[13];
    const float* bhh0 = (const float*)d_in[14];
    const float* Wih1 = (const float*)d_in[15];
    const float* Whh1 = (const float*)d_in[16];
    const float* bih1 = (const float*)d_in[17];
    const float* bhh1 = (const float*)d_in[18];
    const float* Wc1  = (const float*)d_in[19];
    const float* bc1  = (const float*)d_in[20];
    const float* Wc2  = (const float*)d_in[21];
    const float* bc2  = (const float*)d_in[22];
    float* out = (float*)d_out;

    // workspace (floats): ~90.4 MB. Layout unchanged.
    float* wsp   = (float*)d_ws;
    float* adjn  = wsp;                           // 4096 (written by prep block 234)
    short* wihf0G = (short*)(adjn + 4096);        // 65536 shorts  (32768 floats)
    short* wihf1G = (short*)(adjn + 4096 + 32768);// 131072 shorts (65536 floats)
    short* adjfG  = (short*)(adjn + 4096 + 98304);// 3072 shorts
    short* wcatfG = adjfG + 3072;                 // 16384 shorts
    short* whhf0G = wcatfG + 16384;               // 131072 shorts
    short* whhf1G = whhf0G + 131072;              // 131072 shorts  (=> 140800 floats total)
    float* feats = adjn + 4096 + 98304 + 140800;  // 2031616
    float* out0  = feats + 2031616;               // 4063232
    float* xg    = out0  + 4063232;               // 16252928 (shared by both layers)

    prep_kernel<<<235, 256, 0, stream>>>(Wih0, Whh0, Wih1, Whh1, ew, adjn, Ws2, Wn2,
                                         wihf0G, wihf1G, adjfG, wcatfG, whhf0G, whhf1G);
    sage_mfma<<<SGRID, 256, 0, stream>>>(I, Q, adjn, Wn1, bn1, Ws1, bs1,
                                         bn2, bs2, adjfG, wcatfG, feats);
    gemm_mfma<64><<<dim3(496, 4), 256, 0, stream>>>(feats, wihf0G, bih0, bhh0, xg);
    lstm_mfma<false><<<256, 512, 0, stream>>>(xg, whhf0G, out0,
                                              nullptr, nullptr, nullptr, nullptr, nullptr);
    gemm_mfma<128><<<dim3(496, 4), 256, 0, stream>>>(out0, wihf1G, bih1, bhh1, xg);
    lstm_mfma<true><<<256, 512, 0, stream>>>(xg, whhf1G, nullptr,
                                             Wc1, bc1, Wc2, bc2, out);
}

// Round 19
// 381.747 us; speedup vs baseline: 1.0221x; 1.0221x over previous
//
#include <hip/hip_runtime.h>
#include <hip/hip_bf16.h>
#include <math.h>

#define L_SZ 1024
#define STRIDE_ 32
#define WIN 8
#define PNUM 31
#define NPATCH 31744   // 1024 batches x 31 patches
#define SGRID 512      // 256 CU x 2 blocks/CU co-resident ((256,2)-pinned residency)

// LDS row strides (in shorts). dword strides = 36/68 = 4 mod 32 -> 2-way banks (free).
#define X1TS 72
#define CAS  136

typedef __attribute__((ext_vector_type(8))) short short8;
typedef __attribute__((ext_vector_type(4))) short short4v;
typedef __attribute__((ext_vector_type(4))) float f32x4;

#define MFMA16(a, b, c) __builtin_amdgcn_mfma_f32_16x16x32_bf16(a, b, c, 0, 0, 0)

// LDS-only barrier: waits lgkmcnt only; vmem stays in flight across the
// barrier (compiler inserts vmcnt waits before first USE of loaded values).
// sched_barrier(0) fences both sides (rule #18).
__device__ __forceinline__ void bar_lds() {
    __builtin_amdgcn_sched_barrier(0);
    asm volatile("s_waitcnt lgkmcnt(0)" ::: "memory");
    __builtin_amdgcn_s_barrier();
    __builtin_amdgcn_sched_barrier(0);
}

__device__ __forceinline__ float sigf(float x) { return 1.0f / (1.0f + __expf(-x)); }
__device__ __forceinline__ float tanhfast(float x) {
    float ax = fabsf(x);
    float t = __expf(-2.0f * ax);
    return copysignf((1.0f - t) / (1.0f + t), x);
}
__device__ __forceinline__ short f2bf(float f) {
    __hip_bfloat16 h = __float2bfloat16(f);   // RNE
    return *reinterpret_cast<short*>(&h);
}
__device__ __forceinline__ float bf2f(short s) {
    __hip_bfloat16 h = *reinterpret_cast<__hip_bfloat16*>(&s);
    return __bfloat162float(h);
}

// row degree-inverse of the banded sigmoid adjacency, ascending-j order —
// bit-identical to the original adj_kernel (out-of-band terms were exact 0.0f).
__device__ __forceinline__ float deg_inv_row(const float* __restrict__ ew, int row) {
    float s = 0.f;
    #pragma unroll
    for (int d = 0; d < 17; ++d) {
        int j = row + d - WIN;
        if (j >= 0 && j < 64 && d != WIN) s += sigf(ew[row * 64 + j]);
    }
    return (s > 0.f) ? 1.0f / s : 0.f;
}

// ---------------------------------------------------------------------------
// prep (R33): frags + adjn (block 234). Unchanged.
//   blocks   0..31  : wihf0 | 32..95 : wihf1 | 96..105 : sage frags
//   blocks 106..169 : Whh0  | 170..233 : Whh1 | 234 : adjn
// ---------------------------------------------------------------------------
__global__ void prep_kernel(const float* __restrict__ Wih0, const float* __restrict__ Whh0,
                            const float* __restrict__ Wih1, const float* __restrict__ Whh1,
                            const float* __restrict__ ew, float* __restrict__ adjn,
                            const float* __restrict__ Ws2, const float* __restrict__ Wn2,
                            short* __restrict__ wihf0G, short* __restrict__ wihf1G,
                            short* __restrict__ adjfG, short* __restrict__ wcatfG,
                            short* __restrict__ whhf0G, short* __restrict__ whhf1G) {
    int bid = blockIdx.x, tid = threadIdx.x;
    if (bid < 32) {                      // wihf0: f = nt*4 + ks*2 + hl (K32=2)
        int t = bid * 256 + tid;         // 0..8191
        int f = t >> 6, l = t & 63;
        int hl = f & 1, ks = (f >> 1) & 1, nt = f >> 2;
        int q = l >> 4, l15 = l & 15;
        short8 v;
        #pragma unroll
        for (int e = 0; e < 8; ++e) {
            float src = Wih0[(size_t)(nt * 16 + l15) * 64 + ks * 32 + 8 * q + e];
            short hi = f2bf(src);
            v[e] = hl ? f2bf(src - bf2f(hi)) : hi;
        }
        *(short8*)(wihf0G + (size_t)f * 512 + l * 8) = v;
        return;
    }
    if (bid < 96) {                      // wihf1: f = nt*8 + ks*2 + hl (K32=4)
        int t = (bid - 32) * 256 + tid;  // 0..16383
        int f = t >> 6, l = t & 63;
        int hl = f & 1, ks = (f >> 1) & 3, nt = f >> 3;
        int q = l >> 4, l15 = l & 15;
        short8 v;
        #pragma unroll
        for (int e = 0; e < 8; ++e) {
            float src = Wih1[(size_t)(nt * 16 + l15) * 128 + ks * 32 + 8 * q + e];
            short hi = f2bf(src);
            v[e] = hl ? f2bf(src - bf2f(hi)) : hi;
        }
        *(short8*)(wihf1G + (size_t)f * 512 + l * 8) = v;
        return;
    }
    if (bid < 106) {
        int t = (bid - 96) * 256 + tid;
        if (t >= 2432) return;
        int f = t >> 6, l = t & 63;
        int q = l >> 4, l15 = l & 15;
        short8 v;
        if (f < 6) {
            const int ntT[6] = {0, 1, 1, 2, 2, 3};
            const int ksT[6] = {0, 0, 1, 0, 1, 1};
            int row = l15 + 16 * ntT[f], col = 8 * q + 32 * ksT[f];
            float dinv = deg_inv_row(ew, row);
            #pragma unroll
            for (int e = 0; e < 8; ++e) {
                int c = col + e;
                int dd = row - c; dd = dd < 0 ? -dd : dd;
                float av = (dd <= WIN && dd != 0) ? sigf(ew[row * 64 + c]) * dinv : 0.f;
                v[e] = f2bf(av);
            }
            *(short8*)(adjfG + ((size_t)f * 64 + l) * 8) = v;
        } else {
            int fi = f - 6;
            int isLo = fi >= 16;
            int ff = isLo ? fi - 16 : fi;
            int nt = ff >> 2, ks = ff & 3;
            int oo = l15 + 16 * nt;
            #pragma unroll
            for (int e = 0; e < 8; ++e) {
                int k = 32 * ks + 8 * q + e;
                float src = (k < 64) ? Ws2[oo * 64 + k] : Wn2[oo * 64 + (k - 64)];
                short hi = f2bf(src);
                v[e] = isLo ? f2bf(src - bf2f(hi)) : hi;
            }
            *(short8*)(wcatfG + ((size_t)fi * 64 + l) * 8) = v;
        }
        return;
    }
    if (bid < 234) {
        int layer = (bid < 170) ? 0 : 1;
        int base = layer ? 170 : 106;
        const float* Whh = layer ? Whh1 : Whh0;
        short* dst = layer ? whhf1G : whhf0G;
        int t = (bid - base) * 256 + tid;    // 0..16383
        int frag = t >> 6, l = t & 63;
        int hl = frag & 1, ks = (frag >> 1) & 3, NT = frag >> 3;
        int g = NT * 16 + (l & 15);
        int kbase = ks * 32 + (l >> 4) * 8;
        short8 v;
        #pragma unroll
        for (int e = 0; e < 8; ++e) {
            float src = Whh[(size_t)g * 128 + kbase + e];
            short hi = f2bf(src);
            v[e] = hl ? f2bf(src - bf2f(hi)) : hi;
        }
        *(short8*)(dst + (size_t)t * 8) = v;
        return;
    }
    {
        // block 234: adjn[i][j] — same expression & order as the old adj_kernel.
        int i = tid >> 2;                 // row 0..63
        int j0 = (tid & 3) * 16;          // 16 cols per thread
        float dinv = deg_inv_row(ew, i);
        #pragma unroll
        for (int e = 0; e < 16; ++e) {
            int j = j0 + e;
            int d = i - j; d = d < 0 ? -d : d;
            float a = (d <= WIN && d != 0) ? sigf(ew[i * 64 + j]) : 0.f;
            adjn[i * 64 + j] = a * dinv;
        }
    }
}

// ---------------------------------------------------------------------------
// Persistent fused SAGE, bf16 MFMA. (R33 form — control; 180.5 us, VGPR 116.)
// ---------------------------------------------------------------------------
__launch_bounds__(256, 2)
__global__ void sage_mfma(const float* __restrict__ I, const float* __restrict__ Q,
                          const float* __restrict__ adjn,
                          const float* __restrict__ Wn1, const float* __restrict__ bn1,
                          const float* __restrict__ Ws1, const float* __restrict__ bs1,
                          const float* __restrict__ bn2, const float* __restrict__ bs2,
                          const short* __restrict__ adjfG, const short* __restrict__ wcatfG,
                          float* __restrict__ feats) {
    __shared__ __align__(16) short s_x1T[2][64 * X1TS];  // x1^T [o][i] bf16, per patch
    __shared__ __align__(16) short s_cat[2][64 * CAS];   // [i][x1|n1] bf16, per patch

    const int tid = threadIdx.x;
    const int w = tid >> 6, l = tid & 63, q = l >> 4, l15 = l & 15;

    const bool hasKs0 = (w <= 2);
    const bool hasKs1 = (w >= 1);
    const int idx0 = (w == 0) ? 0 : (w == 1 ? 1 : 3);
    const int idx1 = (w == 1) ? 2 : (w == 2 ? 4 : 5);
    short8 adjB0 = {}, adjB1 = {};
    if (hasKs0) adjB0 = *(const short8*)(adjfG + ((size_t)idx0 * 64 + l) * 8);
    if (hasKs1) adjB1 = *(const short8*)(adjfG + ((size_t)idx1 * 64 + l) * 8);

    short8 whf[4], wlf[4];
    #pragma unroll
    for (int ks = 0; ks < 4; ++ks) {
        whf[ks] = *(const short8*)(wcatfG + ((size_t)(w * 4 + ks) * 64 + l) * 8);
        wlf[ks] = *(const short8*)(wcatfG + ((size_t)(w * 4 + ks + 16) * 64 + l) * 8);
    }
    const int oo = l15 + 16 * w;
    const float bo = bs2[oo] + bn2[oo];

    // adjn band in registers: lane l = row i; zeros outside [0,64)
    float areg[17];
    #pragma unroll
    for (int d = 0; d < 17; ++d) {
        int j = l + d - WIN;
        areg[d] = (j >= 0 && j < 64) ? adjn[l * 64 + j] : 0.f;
    }

    float x0a[2], x0b[2];
    #pragma unroll
    for (int P = 0; P < 2; ++P) {
        int m = blockIdx.x + P * 512;
        int b = m / PNUM, p = m % PNUM;
        x0a[P] = I[(size_t)b * L_SZ + p * STRIDE_ + l];
        x0b[P] = Q[(size_t)b * L_SZ + p * STRIDE_ + l];
    }

    for (int it = 0; it < 31; ++it) {
        const int m0 = it * 1024 + blockIdx.x;

        #pragma unroll
        for (int P = 0; P < 2; ++P) {
            float n0a = 0.f, n0b = 0.f;
            #pragma unroll
            for (int d = 0; d < 17; ++d) {
                int j = l + d - WIN;
                float xa = __shfl(x0a[P], j, 64);
                float xb = __shfl(x0b[P], j, 64);
                n0a += areg[d] * xa;
                n0b += areg[d] * xb;
            }
            union { short s[16]; short8 v[2]; } pk;
            #pragma unroll
            for (int t = 0; t < 16; ++t) {
                int o = w * 16 + t;
                float2 wsv = ((const float2*)Ws1)[o];
                float2 wnv = ((const float2*)Wn1)[o];
                float v = bs1[o] + bn1[o] + wsv.x * x0a[P] + wsv.y * x0b[P]
                                          + wnv.x * n0a + wnv.y * n0b;
                v = fmaxf(v, 0.f);
                short bv = f2bf(v);
                s_x1T[P][o * X1TS + l] = bv;
                pk.s[t] = bv;
            }
            *(short8*)&s_cat[P][l * CAS + w * 16]     = pk.v[0];
            *(short8*)&s_cat[P][l * CAS + w * 16 + 8] = pk.v[1];
        }

        if (it + 1 < 31) {
            #pragma unroll
            for (int P = 0; P < 2; ++P) {
                int m = (it + 1) * 1024 + blockIdx.x + P * 512;
                int b = m / PNUM, p = m % PNUM;
                x0a[P] = I[(size_t)b * L_SZ + p * STRIDE_ + l];
                x0b[P] = Q[(size_t)b * L_SZ + p * STRIDE_ + l];
            }
        }
        bar_lds();

        #pragma unroll
        for (int P = 0; P < 2; ++P) {
            #pragma unroll
            for (int ot = 0; ot < 4; ++ot) {
                f32x4 c = {0.f, 0.f, 0.f, 0.f};
                if (hasKs0) {
                    short8 a = *(const short8*)&s_x1T[P][(16 * ot + l15) * X1TS + 8 * q];
                    c = MFMA16(a, adjB0, c);
                }
                if (hasKs1) {
                    short8 a = *(const short8*)&s_x1T[P][(16 * ot + l15) * X1TS + 8 * q + 32];
                    c = MFMA16(a, adjB1, c);
                }
                short4v nv;
                nv[0] = f2bf(c[0]); nv[1] = f2bf(c[1]);
                nv[2] = f2bf(c[2]); nv[3] = f2bf(c[3]);
                *(short4v*)&s_cat[P][(16 * w + l15) * CAS + 64 + 16 * ot + 4 * q] = nv;
            }
        }
        bar_lds();

        #pragma unroll
        for (int P = 0; P < 2; ++P) {
            f32x4 z = {0.f, 0.f, 0.f, 0.f};
            f32x4 acc2[4] = {z, z, z, z};
            #pragma unroll
            for (int it2 = 0; it2 < 4; ++it2) {
                short8 a2[4];
                #pragma unroll
                for (int ks = 0; ks < 4; ++ks)
                    a2[ks] = *(const short8*)&s_cat[P][(16 * it2 + l15) * CAS + 32 * ks + 8 * q];
                #pragma unroll
                for (int ks = 0; ks < 4; ++ks) {
                    acc2[it2] = MFMA16(a2[ks], whf[ks], acc2[it2]);
                    acc2[it2] = MFMA16(a2[ks], wlf[ks], acc2[it2]);
                }
            }
            float total = 0.f;
            #pragma unroll
            for (int it2 = 0; it2 < 4; ++it2) {
                float s = fmaxf(acc2[it2][0] + bo, 0.f) + fmaxf(acc2[it2][1] + bo, 0.f)
                        + fmaxf(acc2[it2][2] + bo, 0.f) + fmaxf(acc2[it2][3] + bo, 0.f);
                s += __shfl_xor(s, 16);
                s += __shfl_xor(s, 32);
                total += s;
            }
            if (l < 16)
                feats[(size_t)(m0 + P * 512) * 64 + 16 * w + l15] = total;
        }
        bar_lds();
    }
}

// ---------------------------------------------------------------------------
// GEMM v2 (R27): MFMA with double-bf16 (hi/lo) on BOTH operands, 3-term
// product. C[M x 512] = A[M x K] @ Wih^T + b1 + b2. (control)
// ---------------------------------------------------------------------------
template <int K>
__launch_bounds__(256, 2)
__global__ void gemm_mfma(const float* __restrict__ A, const short* __restrict__ wihfG,
                          const float* __restrict__ bias1, const float* __restrict__ bias2,
                          float* __restrict__ C) {
    constexpr int K32 = K / 32;
    constexpr int K4 = K / 4;
    constexpr int AS = (K == 64) ? 72 : 136;   // row stride in shorts (4-mod-32 dwords)
    __shared__ __align__(16) short s_ah[64 * AS];
    __shared__ __align__(16) short s_al[64 * AS];
    const int tid = threadIdx.x;
    const int w = tid >> 6, l = tid & 63, q = l >> 4, l15 = l & 15;
    const int m0 = blockIdx.x * 64;
    const int j0 = blockIdx.y * 128;

    // stage A hi/lo into LDS (64 rows x K floats -> 2x bf16)
    {
        const float4* Ag = (const float4*)(A + (size_t)m0 * K);
        for (int e = tid; e < 16 * K; e += 256) {
            int row = e / K4, c4 = e % K4;
            float4 v = Ag[row * K4 + c4];
            short4v h, lo;
            h[0] = f2bf(v.x); lo[0] = f2bf(v.x - bf2f(h[0]));
            h[1] = f2bf(v.y); lo[1] = f2bf(v.y - bf2f(h[1]));
            h[2] = f2bf(v.z); lo[2] = f2bf(v.z - bf2f(h[2]));
            h[3] = f2bf(v.w); lo[3] = f2bf(v.w - bf2f(h[3]));
            *(short4v*)&s_ah[row * AS + c4 * 4] = h;
            *(short4v*)&s_al[row * AS + c4 * 4] = lo;
        }
    }

    // B frags: wave w owns global ntiles (j0/16 + 2w) and (j0/16 + 2w + 1)
    short8 bh[2][K32], bl[2][K32];
    #pragma unroll
    for (int c = 0; c < 2; ++c) {
        int nt = (j0 >> 4) + 2 * w + c;
        #pragma unroll
        for (int ks = 0; ks < K32; ++ks) {
            bh[c][ks] = *(const short8*)(wihfG + (((size_t)(nt * K32 + ks) * 2 + 0) * 64 + l) * 8);
            bl[c][ks] = *(const short8*)(wihfG + (((size_t)(nt * K32 + ks) * 2 + 1) * 64 + l) * 8);
        }
    }
    __syncthreads();

    f32x4 z = {0.f, 0.f, 0.f, 0.f};
    #pragma unroll
    for (int mt = 0; mt < 4; ++mt) {
        f32x4 acc[2] = {z, z};
        #pragma unroll
        for (int ks = 0; ks < K32; ++ks) {
            short8 ah = *(const short8*)&s_ah[(16 * mt + l15) * AS + 32 * ks + 8 * q];
            short8 al = *(const short8*)&s_al[(16 * mt + l15) * AS + 32 * ks + 8 * q];
            #pragma unroll
            for (int c = 0; c < 2; ++c) {
                acc[c] = MFMA16(ah, bh[c][ks], acc[c]);
                acc[c] = MFMA16(al, bh[c][ks], acc[c]);
                acc[c] = MFMA16(ah, bl[c][ks], acc[c]);
            }
        }
        #pragma unroll
        for (int c = 0; c < 2; ++c) {
            int col = j0 + (2 * w + c) * 16 + l15;
            float bo = bias1[col] + bias2[col];
            #pragma unroll
            for (int reg = 0; reg < 4; ++reg) {
                int row = m0 + 16 * mt + 4 * q + reg;
                C[(size_t)row * 512 + col] = acc[c][reg] + bo;
            }
        }
    }
}

// ---------------------------------------------------------------------------
// LSTM recurrence v10 (R34): v9 + double-buffered s_h -> ONE barrier/step.
// v9's barrier #1 was a WAR fence (af reads of s_h must retire before this
// step's gate writes). With s_h[2]: step t reads s_h[t&1], writes
// s_h[(t&1)^1]; the WAR pair (read buf c at t, write buf c at t+1) is
// separated by the end-of-step barrier, whose lgkmcnt(0) also retires the
// reads. RAW edge (write t -> read t+1) keeps the remaining barrier. Rows
// 4..15 of BOTH buffers zero-init (A-operand). Final h (t=30, cur=0) lands
// in s_h[1] -> epilogue reads buffer 1. Math unchanged -> bit-identical.
// ---------------------------------------------------------------------------
#define HS 136    // s_h row stride in shorts (68 dwords = 4 mod 32)

template <bool FINAL>
__launch_bounds__(512)
__global__ void lstm_mfma(const float* __restrict__ xg, const short* __restrict__ whhfG,
                          float* __restrict__ out0,
                          const float* __restrict__ Wc1, const float* __restrict__ bc1,
                          const float* __restrict__ Wc2, const float* __restrict__ bc2,
                          float* __restrict__ out) {
    __shared__ __align__(16) short s_h[2][16 * HS]; // h bf16 [m][k]; rows 4..15 stay 0
    __shared__ __align__(16) float s_hid[4 * 68];
    const int tid = threadIdx.x;
    const int w = tid >> 6, l = tid & 63, quad = l >> 4, l15 = l & 15;
    const int b0 = blockIdx.x * 4;                  // 4 batch rows per block
    const int j = 16 * w + l15;                     // this lane's hidden unit 0..127
    const int row = quad;                           // this lane's batch row 0..3

    // weight frags for output tiles NT = w + 8*nt  (nt = 0:i, 1:f, 2:g, 3:o)
    short8 whf[16], wlf[16];
    #pragma unroll
    for (int nt = 0; nt < 4; ++nt)
        #pragma unroll
        for (int ks = 0; ks < 4; ++ks) {
            size_t NT = (size_t)(w + 8 * nt);
            whf[nt * 4 + ks] = *(const short8*)(whhfG + (((NT * 4 + ks) * 2 + 0) * 64 + l) * 8);
            wlf[nt * 4 + ks] = *(const short8*)(whhfG + (((NT * 4 + ks) * 2 + 1) * 64 + l) * 8);
        }

    float c0 = 0.f;
    for (int e = tid; e < 2 * 16 * HS; e += 512) ((short*)s_h)[e] = 0;
    __syncthreads();

    // prefetch t=0 xgv for (row, unit j)
    float xgv[4];
    {
        size_t base = ((size_t)(b0 + row) * PNUM + 0) * 512 + j;
        xgv[0] = xg[base];
        xgv[1] = xg[base + 128];
        xgv[2] = xg[base + 256];
        xgv[3] = xg[base + 384];
    }

    for (int t = 0; t < 31; ++t) {
        const short* __restrict__ hin  = s_h[t & 1];
        short* __restrict__       hout = s_h[(t & 1) ^ 1];

        short8 af[4];
        #pragma unroll
        for (int ks = 0; ks < 4; ++ks)
            af[ks] = *(const short8*)&hin[l15 * HS + ks * 32 + quad * 8];

        f32x4 z = {0.f, 0.f, 0.f, 0.f};
        f32x4 acc[4] = {z, z, z, z};
        #pragma unroll
        for (int nt = 0; nt < 4; ++nt)
            #pragma unroll
            for (int ks = 0; ks < 4; ++ks) {
                acc[nt] = MFMA16(af[ks], whf[nt * 4 + ks], acc[nt]);
                acc[nt] = MFMA16(af[ks], wlf[nt * 4 + ks], acc[nt]);
            }

        // issue next-step xgv loads: in flight across gates + barrier
        float nx0 = 0.f, nx1 = 0.f, nx2 = 0.f, nx3 = 0.f;
        if (t + 1 < 31) {
            size_t base = ((size_t)(b0 + row) * PNUM + (t + 1)) * 512 + j;
            nx0 = xg[base];
            nx1 = xg[base + 128];
            nx2 = xg[base + 256];
            nx3 = xg[base + 384];
        }

        // shuffle-broadcast: gate nt for (row, j) = acc[nt][row], held by lane l15
        float g4[4];
        #pragma unroll
        for (int nt = 0; nt < 4; ++nt) {
            float s0 = __shfl(acc[nt][0], l15, 64);
            float s1 = __shfl(acc[nt][1], l15, 64);
            float s2 = __shfl(acc[nt][2], l15, 64);
            float s3 = __shfl(acc[nt][3], l15, 64);
            g4[nt] = (quad == 0) ? s0 : (quad == 1) ? s1 : (quad == 2) ? s2 : s3;
        }

        // gates: every lane handles one (row, unit); write to the OTHER buffer
        {
            float gi = xgv[0] + g4[0];
            float gf = xgv[1] + g4[1];
            float gg = xgv[2] + g4[2];
            float go = xgv[3] + g4[3];
            float cn = sigf(gf) * c0 + sigf(gi) * tanhfast(gg);
            float h = sigf(go) * tanhfast(cn);
            c0 = cn;
            hout[row * HS + j] = f2bf(h);
            if (!FINAL)
                out0[((size_t)(b0 + row) * PNUM + t) * 128 + j] = h;
        }
        xgv[0] = nx0; xgv[1] = nx1; xgv[2] = nx2; xgv[3] = nx3;
        bar_lds();   // single barrier/step: RAW (hout -> next hin) + retires af reads
    }

    if (FINAL) {
        // final h (t=30, cur=0) was written to s_h[1]
        if (tid < 256) {
            int rr = tid >> 6, uu = tid & 63;
            float acc = bc1[uu];
            const float* wv = Wc1 + (size_t)uu * 128;
            #pragma unroll 8
            for (int k = 0; k < 128; ++k) acc += wv[k] * bf2f(s_h[1][rr * HS + k]);
            s_hid[rr * 68 + uu] = fmaxf(acc, 0.f);
        }
        __syncthreads();
        if (tid < 44) {
            int rr = tid / 11, cc = tid % 11;
            float acc = bc2[cc];
            #pragma unroll
            for (int uu = 0; uu < 64; ++uu) acc += Wc2[cc * 64 + uu] * s_hid[rr * 68 + uu];
            out[(size_t)(b0 + rr) * 11 + cc] = acc;
        }
    }
}

// ---------------------------------------------------------------------------
extern "C" void kernel_launch(void* const* d_in, const int* in_sizes, int n_in,
                              void* d_out, int out_size, void* d_ws, size_t ws_size,
                              hipStream_t stream) {
    (void)in_sizes; (void)n_in; (void)out_size; (void)ws_size;
    const float* I    = (const float*)d_in[0];
    const float* Q    = (const float*)d_in[1];
    const float* ew   = (const float*)d_in[2];
    const float* Wn1  = (const float*)d_in[3];
    const float* bn1  = (const float*)d_in[4];
    const float* Ws1  = (const float*)d_in[5];
    const float* bs1  = (const float*)d_in[6];
    const float* Wn2  = (const float*)d_in[7];
    const float* bn2  = (const float*)d_in[8];
    const float* Ws2  = (const float*)d_in[9];
    const float* bs2  = (const float*)d_in[10];
    const float* Wih0 = (const float*)d_in[11];
    const float* Whh0 = (const float*)d_in[12];
    const float* bih0 = (const float*)d_in[13];
    const float* bhh0 = (const float*)d_in[14];
    const float* Wih1 = (const float*)d_in[15];
    const float* Whh1 = (const float*)d_in[16];
    const float* bih1 = (const float*)d_in[17];
    const float* bhh1 = (const float*)d_in[18];
    const float* Wc1  = (const float*)d_in[19];
    const float* bc1  = (const float*)d_in[20];
    const float* Wc2  = (const float*)d_in[21];
    const float* bc2  = (const float*)d_in[22];
    float* out = (float*)d_out;

    // workspace (floats): ~90.4 MB. Layout unchanged.
    float* wsp   = (float*)d_ws;
    float* adjn  = wsp;                           // 4096 (written by prep block 234)
    short* wihf0G = (short*)(adjn + 4096);        // 65536 shorts  (32768 floats)
    short* wihf1G = (short*)(adjn + 4096 + 32768);// 131072 shorts (65536 floats)
    short* adjfG  = (short*)(adjn + 4096 + 98304);// 3072 shorts
    short* wcatfG = adjfG + 3072;                 // 16384 shorts
    short* whhf0G = wcatfG + 16384;               // 131072 shorts
    short* whhf1G = whhf0G + 131072;              // 131072 shorts  (=> 140800 floats total)
    float* feats = adjn + 4096 + 98304 + 140800;  // 2031616
    float* out0  = feats + 2031616;               // 4063232
    float* xg    = out0  + 4063232;               // 16252928 (shared by both layers)

    prep_kernel<<<235, 256, 0, stream>>>(Wih0, Whh0, Wih1, Whh1, ew, adjn, Ws2, Wn2,
                                         wihf0G, wihf1G, adjfG, wcatfG, whhf0G, whhf1G);
    sage_mfma<<<SGRID, 256, 0, stream>>>(I, Q, adjn, Wn1, bn1, Ws1, bs1,
                                         bn2, bs2, adjfG, wcatfG, feats);
    gemm_mfma<64><<<dim3(496, 4), 256, 0, stream>>>(feats, wihf0G, bih0, bhh0, xg);
    lstm_mfma<false><<<256, 512, 0, stream>>>(xg, whhf0G, out0,
                                              nullptr, nullptr, nullptr, nullptr, nullptr);
    gemm_mfma<128><<<dim3(496, 4), 256, 0, stream>>>(out0, wihf1G, bih1, bhh1, xg);
    lstm_mfma<true><<<256, 512, 0, stream>>>(xg, whhf1G, nullptr,
                                             Wc1, bc1, Wc2, bc2, out);
}